// Round 1
// baseline (1042.704 us; speedup 1.0000x reference)
//
#include <hip/hip_runtime.h>
#include <cfloat>
#include <cmath>

// Problem constants (derived from reference): F_IN=128, HID=512, G=256
#define F_IN 128
#define HID 512

// ---------------- small utility kernels ----------------

__global__ void zero2_kernel(int* __restrict__ a, int* __restrict__ b, int n) {
    int i = blockIdx.x * blockDim.x + threadIdx.x;
    if (i < n) { a[i] = 0; b[i] = 0; }
}

__global__ void count_in_kernel(const int* __restrict__ dst, int* __restrict__ cnt, int E) {
    int e = blockIdx.x * blockDim.x + threadIdx.x;
    if (e < E) atomicAdd(&cnt[dst[e]], 1);
}

// single-block Hillis-Steele scan over chunks of 1024 (exclusive prefix sum)
__global__ void scan_kernel(const int* __restrict__ cnt, int* __restrict__ offs, int n) {
    __shared__ int buf[1024];
    __shared__ int carry_s;
    if (threadIdx.x == 0) carry_s = 0;
    __syncthreads();
    for (int base = 0; base < n; base += 1024) {
        int i = base + threadIdx.x;
        int v = (i < n) ? cnt[i] : 0;
        buf[threadIdx.x] = v;
        __syncthreads();
        for (int s = 1; s < 1024; s <<= 1) {
            int t = (threadIdx.x >= s) ? buf[threadIdx.x - s] : 0;
            __syncthreads();
            buf[threadIdx.x] += t;
            __syncthreads();
        }
        int total = buf[1023];                    // inclusive total of this chunk
        if (i < n) offs[i] = carry_s + buf[threadIdx.x] - v;  // exclusive
        __syncthreads();                           // all carry_s reads done
        if (threadIdx.x == 0) carry_s += total;
        __syncthreads();
    }
}

__global__ void dis_kernel(const int* __restrict__ cnt, float* __restrict__ dis, int n,
                           int* __restrict__ offs, int E) {
    int i = blockIdx.x * blockDim.x + threadIdx.x;
    if (i < n) dis[i] = rsqrtf((float)(cnt[i] + 1));   // +1 self-loop; deg>=1 always
    if (i == 0) offs[n] = E;
}

__global__ void fill_csr_kernel(const int* __restrict__ src, const int* __restrict__ dst,
                                const int* __restrict__ offs, int* __restrict__ cursor,
                                int* __restrict__ csr, int E) {
    int e = blockIdx.x * blockDim.x + threadIdx.x;
    if (e < E) {
        int d = dst[e];
        int p = atomicAdd(&cursor[d], 1);
        csr[offs[d] + p] = src[e];
    }
}

// batch is sorted; starts[g] = first node index with batch >= g; starts[G] = n
__global__ void starts_kernel(const int* __restrict__ batch, int* __restrict__ starts,
                              int n, int G) {
    int i = blockIdx.x * blockDim.x + threadIdx.x;
    if (i >= n) return;
    int b = batch[i];
    if (i == 0) {
        for (int g = 0; g <= b; g++) starts[g] = 0;
    } else {
        int bp = batch[i - 1];
        for (int g = bp + 1; g <= b; g++) starts[g] = i;
    }
    if (i == n - 1) {
        for (int g = b + 1; g <= G; g++) starts[g] = n;
    }
}

// ---------------- aggregation: out_i = dis_i * (dis_i*H_i + sum_j dis_j*H_j) -------------
// F = 128 version (for input x): one block (64 threads) per node, float2 per thread
__global__ void agg_f128_kernel(const float* __restrict__ X, const float* __restrict__ dis,
                                const int* __restrict__ offs, const int* __restrict__ csr,
                                float* __restrict__ out, int n) {
    int i = blockIdx.x;
    int t = threadIdx.x;                     // 0..63
    const float2* X2 = (const float2*)X;
    float di = dis[i];
    float2 h = X2[(size_t)i * 64 + t];
    float ax = di * h.x, ay = di * h.y;
    int e1 = offs[i + 1];
    for (int e = offs[i]; e < e1; e++) {
        int j = csr[e];
        float dj = dis[j];
        float2 hj = X2[(size_t)j * 64 + t];
        ax += dj * hj.x;
        ay += dj * hj.y;
    }
    ((float2*)out)[(size_t)i * 64 + t] = make_float2(di * ax, di * ay);
}

// F = 512 version: one block (128 threads) per node, float4 per thread
__global__ void agg_f512_kernel(const float* __restrict__ H, const float* __restrict__ dis,
                                const int* __restrict__ offs, const int* __restrict__ csr,
                                float* __restrict__ out, int n) {
    int i = blockIdx.x;
    int t = threadIdx.x;                     // 0..127
    const float4* H4 = (const float4*)H;
    float di = dis[i];
    float4 h = H4[(size_t)i * 128 + t];
    float ax = di * h.x, ay = di * h.y, az = di * h.z, aw = di * h.w;
    int e1 = offs[i + 1];
    for (int e = offs[i]; e < e1; e++) {
        int j = csr[e];
        float dj = dis[j];
        float4 hj = H4[(size_t)j * 128 + t];
        ax += dj * hj.x;
        ay += dj * hj.y;
        az += dj * hj.z;
        aw += dj * hj.w;
    }
    float4 o; o.x = di * ax; o.y = di * ay; o.z = di * az; o.w = di * aw;
    ((float4*)out)[(size_t)i * 128 + t] = o;
}

// ---------------- fp32 GEMM: C[M,Nout] = A[M,K] @ W[Nout,K]^T + bias -------------------
#define BM 128
#define BN 64
#define BK 16

__global__ __launch_bounds__(256) void gemm_bias_kernel(
    const float* __restrict__ A, const float* __restrict__ W,
    const float* __restrict__ bias, float* __restrict__ C,
    int M, int K, int Nout) {
    __shared__ float As[BK][BM + 4];
    __shared__ float Ws[BK][BN + 4];
    int m0 = blockIdx.x * BM;
    int n0 = blockIdx.y * BN;
    int tid = threadIdx.x;
    int tx = tid & 15;   // N direction, 16 threads x TN=4 = 64
    int ty = tid >> 4;   // M direction, 16 threads x TM=8 = 128

    float acc[8][4];
    #pragma unroll
    for (int i = 0; i < 8; i++)
        #pragma unroll
        for (int j = 0; j < 4; j++) acc[i][j] = 0.0f;

    for (int k0 = 0; k0 < K; k0 += BK) {
        // A tile: 128 rows x 16 k = 512 float4; each thread 2
        #pragma unroll
        for (int l = 0; l < 2; l++) {
            int idx = tid + l * 256;
            int r = idx >> 2;        // 0..127 row within tile
            int c4 = idx & 3;        // 0..3 float4 within row
            int m = m0 + r;
            float4 v = make_float4(0.f, 0.f, 0.f, 0.f);
            if (m < M) v = *(const float4*)&A[(size_t)m * K + k0 + c4 * 4];
            As[c4 * 4 + 0][r] = v.x;
            As[c4 * 4 + 1][r] = v.y;
            As[c4 * 4 + 2][r] = v.z;
            As[c4 * 4 + 3][r] = v.w;
        }
        // W tile: 64 rows x 16 k = 256 float4; each thread 1
        {
            int r = tid >> 2;
            int c4 = tid & 3;
            float4 v = *(const float4*)&W[(size_t)(n0 + r) * K + k0 + c4 * 4];
            Ws[c4 * 4 + 0][r] = v.x;
            Ws[c4 * 4 + 1][r] = v.y;
            Ws[c4 * 4 + 2][r] = v.z;
            Ws[c4 * 4 + 3][r] = v.w;
        }
        __syncthreads();
        #pragma unroll
        for (int k = 0; k < BK; k++) {
            float4 a0 = *(const float4*)&As[k][ty * 8];
            float4 a1 = *(const float4*)&As[k][ty * 8 + 4];
            float4 w0 = *(const float4*)&Ws[k][tx * 4];
            float a[8] = {a0.x, a0.y, a0.z, a0.w, a1.x, a1.y, a1.z, a1.w};
            float w[4] = {w0.x, w0.y, w0.z, w0.w};
            #pragma unroll
            for (int i = 0; i < 8; i++)
                #pragma unroll
                for (int j = 0; j < 4; j++) acc[i][j] += a[i] * w[j];
        }
        __syncthreads();
    }

    float4 bv = *(const float4*)&bias[n0 + tx * 4];
    #pragma unroll
    for (int i = 0; i < 8; i++) {
        int m = m0 + ty * 8 + i;
        if (m < M) {
            float4 o;
            o.x = acc[i][0] + bv.x;
            o.y = acc[i][1] + bv.y;
            o.z = acc[i][2] + bv.z;
            o.w = acc[i][3] + bv.w;
            *(float4*)&C[(size_t)m * Nout + n0 + tx * 4] = o;
        }
    }
}

// ---------------- pooling: per-layer segment max + fraction positive -------------------
// grid (G, HID/256), block 256. out[g][layer*512+c] = max, out[g][2048+layer*512+c] = frac>0
__global__ void pool_kernel(const float* __restrict__ H, const int* __restrict__ starts,
                            float* __restrict__ out, int layer) {
    int g = blockIdx.x;
    int c = blockIdx.y * 256 + threadIdx.x;   // 0..511
    int s = starts[g], e = starts[g + 1];
    float mx = -INFINITY;
    int pos = 0;
    for (int n = s; n < e; n++) {
        float v = H[(size_t)n * HID + c];
        mx = fmaxf(mx, v);
        pos += (v > 0.0f) ? 1 : 0;
    }
    float cntf = fmaxf((float)(e - s), 1.0f);
    out[(size_t)g * (8 * HID) + layer * HID + c] = mx;
    out[(size_t)g * (8 * HID) + 4 * HID + layer * HID + c] = (float)pos / cntf;
}

// ---------------- launcher ----------------

extern "C" void kernel_launch(void* const* d_in, const int* in_sizes, int n_in,
                              void* d_out, int out_size, void* d_ws, size_t ws_size,
                              hipStream_t stream) {
    const float* x     = (const float*)d_in[0];
    const int*   eidx  = (const int*)d_in[1];    // [2][E]: first E = src, next E = dst
    const int*   batch = (const int*)d_in[2];
    // d_in[3], d_in[4] = lin_W, lin_b : dead code in reference
    const float* W1 = (const float*)d_in[5];
    const float* b1 = (const float*)d_in[6];
    const float* W2 = (const float*)d_in[7];
    const float* b2 = (const float*)d_in[8];
    const float* W3 = (const float*)d_in[9];
    const float* b3 = (const float*)d_in[10];
    const float* W4 = (const float*)d_in[11];
    const float* b4 = (const float*)d_in[12];
    float* out = (float*)d_out;

    const int N = in_sizes[0] / F_IN;            // 20000
    const int E = in_sizes[1] / 2;               // 320000
    const int G = out_size / (8 * HID);          // 256

    const int* src = eidx;
    const int* dst = eidx + E;

    // workspace layout
    char* w = (char*)d_ws;
    float* bufA = (float*)w; w += (size_t)N * HID * sizeof(float);   // agg output / GEMM input
    float* bufH = (float*)w; w += (size_t)N * HID * sizeof(float);   // GEMM output (current h)
    int* cnt    = (int*)w;   w += (size_t)N * sizeof(int);
    int* cursor = (int*)w;   w += (size_t)N * sizeof(int);
    int* offs   = (int*)w;   w += (size_t)(N + 1) * sizeof(int);
    int* csr    = (int*)w;   w += (size_t)E * sizeof(int);
    float* dis  = (float*)w; w += (size_t)N * sizeof(float);
    int* starts = (int*)w;   w += (size_t)(G + 1) * sizeof(int);

    const int TB = 256;
    // ---- graph preprocessing (CSR over dst, degree, dis, graph boundaries) ----
    zero2_kernel<<<(N + TB - 1) / TB, TB, 0, stream>>>(cnt, cursor, N);
    count_in_kernel<<<(E + TB - 1) / TB, TB, 0, stream>>>(dst, cnt, E);
    scan_kernel<<<1, 1024, 0, stream>>>(cnt, offs, N);
    dis_kernel<<<(N + TB - 1) / TB, TB, 0, stream>>>(cnt, dis, N, offs, E);
    fill_csr_kernel<<<(E + TB - 1) / TB, TB, 0, stream>>>(src, dst, offs, cursor, csr, E);
    starts_kernel<<<(N + TB - 1) / TB, TB, 0, stream>>>(batch, starts, N, G);

    dim3 gemm_grid((N + BM - 1) / BM, HID / BN);

    // ---- layer 1: h1 = (A x) @ W1^T + b1 ----
    agg_f128_kernel<<<N, 64, 0, stream>>>(x, dis, offs, csr, bufA, N);
    gemm_bias_kernel<<<gemm_grid, 256, 0, stream>>>(bufA, W1, b1, bufH, N, F_IN, HID);
    pool_kernel<<<dim3(G, HID / 256), 256, 0, stream>>>(bufH, starts, out, 0);

    // ---- layers 2..4: h_k = (A h_{k-1}) @ Wk^T + bk ----
    const float* Ws_[3] = {W2, W3, W4};
    const float* bs_[3] = {b2, b3, b4};
    for (int l = 0; l < 3; l++) {
        agg_f512_kernel<<<N, 128, 0, stream>>>(bufH, dis, offs, csr, bufA, N);
        gemm_bias_kernel<<<gemm_grid, 256, 0, stream>>>(bufA, Ws_[l], bs_[l], bufH, N, HID, HID);
        pool_kernel<<<dim3(G, HID / 256), 256, 0, stream>>>(bufH, starts, out, l + 1);
    }
}

// Round 2
// 733.272 us; speedup vs baseline: 1.4220x; 1.4220x over previous
//
#include <hip/hip_runtime.h>
#include <cfloat>
#include <cmath>

#define F_IN 128
#define HID 512

typedef short bf16x8 __attribute__((ext_vector_type(8)));
typedef float f32x4 __attribute__((ext_vector_type(4)));

// ---- bf16 split helpers (RNE) ----
__device__ static inline void split_bf16(float v, short& hi, short& lo) {
    unsigned u = __float_as_uint(v);
    unsigned r = u + 0x7FFF + ((u >> 16) & 1);
    hi = (short)(r >> 16);
    float hf = __uint_as_float(((unsigned)(unsigned short)hi) << 16);
    float res = v - hf;
    unsigned u2 = __float_as_uint(res);
    unsigned r2 = u2 + 0x7FFF + ((u2 >> 16) & 1);
    lo = (short)(r2 >> 16);
}

__device__ static inline void gload_lds16(const void* g, void* l) {
    __builtin_amdgcn_global_load_lds(
        (const __attribute__((address_space(1))) unsigned int*)g,
        (__attribute__((address_space(3))) unsigned int*)l,
        16, 0, 0);
}

// ---------------- small utility kernels ----------------

__global__ void zero_kernel(int* __restrict__ a, int n) {
    int i = blockIdx.x * blockDim.x + threadIdx.x;
    if (i < n) a[i] = 0;
}

__global__ void count_in_kernel(const int* __restrict__ dst, int* __restrict__ cnt, int E) {
    int e = blockIdx.x * blockDim.x + threadIdx.x;
    if (e < E) atomicAdd(&cnt[dst[e]], 1);
}

// single-block scan (exclusive prefix sum); also writes offs[n] = total
__global__ void scan_kernel(const int* __restrict__ cnt, int* __restrict__ offs, int n) {
    __shared__ int buf[1024];
    __shared__ int carry_s;
    if (threadIdx.x == 0) carry_s = 0;
    __syncthreads();
    for (int base = 0; base < n; base += 1024) {
        int i = base + threadIdx.x;
        int v = (i < n) ? cnt[i] : 0;
        buf[threadIdx.x] = v;
        __syncthreads();
        for (int s = 1; s < 1024; s <<= 1) {
            int t = (threadIdx.x >= s) ? buf[threadIdx.x - s] : 0;
            __syncthreads();
            buf[threadIdx.x] += t;
            __syncthreads();
        }
        int total = buf[1023];
        if (i < n) offs[i] = carry_s + buf[threadIdx.x] - v;
        __syncthreads();
        if (threadIdx.x == 0) carry_s += total;
        __syncthreads();
    }
    if (threadIdx.x == 0) offs[n] = carry_s;
}

__global__ void dis_kernel(const int* __restrict__ offs, float* __restrict__ dis, int n) {
    int i = blockIdx.x * blockDim.x + threadIdx.x;
    if (i < n) dis[i] = rsqrtf((float)(offs[i + 1] - offs[i] + 1));  // +1 self-loop
}

__global__ void fill_csr_kernel(const int* __restrict__ src, const int* __restrict__ dst,
                                const int* __restrict__ offs, int* __restrict__ cursor,
                                unsigned short* __restrict__ csr, int E) {
    int e = blockIdx.x * blockDim.x + threadIdx.x;
    if (e < E) {
        int d = dst[e];
        int p = atomicAdd(&cursor[d], 1);
        csr[offs[d] + p] = (unsigned short)src[e];
    }
}

__global__ void starts_kernel(const int* __restrict__ batch, int* __restrict__ starts,
                              int n, int G) {
    int i = blockIdx.x * blockDim.x + threadIdx.x;
    if (i >= n) return;
    int b = batch[i];
    if (i == 0) {
        for (int g = 0; g <= b; g++) starts[g] = 0;
    } else {
        int bp = batch[i - 1];
        for (int g = bp + 1; g <= b; g++) starts[g] = i;
    }
    if (i == n - 1) {
        for (int g = b + 1; g <= G; g++) starts[g] = n;
    }
}

// W[N][K] fp32 -> bf16 hi/lo planes
__global__ void wconv_kernel(const float* __restrict__ W, short* __restrict__ Whi,
                             short* __restrict__ Wlo, int n) {
    int i = blockIdx.x * blockDim.x + threadIdx.x;
    if (i < n) {
        short h, l;
        split_bf16(W[i], h, l);
        Whi[i] = h;
        Wlo[i] = l;
    }
}

// -------- aggregation + fused bf16-pair conversion --------
// out_i = dis_i * (dis_i*H_i + sum_j dis_j*H_j), written as bf16 hi/lo planes

// F=128 (input x): 64 threads per node, float2 per thread, 4-way pipelined gather
__global__ void agg_f128_kernel(const float* __restrict__ X, const float* __restrict__ dis,
                                const int* __restrict__ offs, const unsigned short* __restrict__ csr,
                                short* __restrict__ Ahi, short* __restrict__ Alo, int n) {
    int i = blockIdx.x;
    int t = threadIdx.x;  // 0..63
    const float2* X2 = (const float2*)X;
    float di = dis[i];
    float2 h = X2[(size_t)i * 64 + t];
    float ax = di * h.x, ay = di * h.y;
    int e = offs[i], e1 = offs[i + 1];
    for (; e + 4 <= e1; e += 4) {
        int j0 = csr[e], j1 = csr[e + 1], j2 = csr[e + 2], j3 = csr[e + 3];
        float d0 = dis[j0], d1 = dis[j1], d2 = dis[j2], d3 = dis[j3];
        float2 r0 = X2[(size_t)j0 * 64 + t];
        float2 r1 = X2[(size_t)j1 * 64 + t];
        float2 r2 = X2[(size_t)j2 * 64 + t];
        float2 r3 = X2[(size_t)j3 * 64 + t];
        ax += d0 * r0.x + d1 * r1.x + d2 * r2.x + d3 * r3.x;
        ay += d0 * r0.y + d1 * r1.y + d2 * r2.y + d3 * r3.y;
    }
    for (; e < e1; e++) {
        int j = csr[e];
        float d = dis[j];
        float2 r = X2[(size_t)j * 64 + t];
        ax += d * r.x;
        ay += d * r.y;
    }
    ax *= di; ay *= di;
    short hx, lx, hy, ly;
    split_bf16(ax, hx, lx);
    split_bf16(ay, hy, ly);
    *(short2*)&Ahi[(size_t)i * F_IN + t * 2] = make_short2(hx, hy);
    *(short2*)&Alo[(size_t)i * F_IN + t * 2] = make_short2(lx, ly);
}

// F=512: 128 threads per node, float4 per thread, 4-way pipelined gather
__global__ void agg_f512_kernel(const float* __restrict__ H, const float* __restrict__ dis,
                                const int* __restrict__ offs, const unsigned short* __restrict__ csr,
                                short* __restrict__ Ahi, short* __restrict__ Alo, int n) {
    int i = blockIdx.x;
    int t = threadIdx.x;  // 0..127
    const float4* H4 = (const float4*)H;
    float di = dis[i];
    float4 h = H4[(size_t)i * 128 + t];
    float ax = di * h.x, ay = di * h.y, az = di * h.z, aw = di * h.w;
    int e = offs[i], e1 = offs[i + 1];
    for (; e + 4 <= e1; e += 4) {
        int j0 = csr[e], j1 = csr[e + 1], j2 = csr[e + 2], j3 = csr[e + 3];
        float d0 = dis[j0], d1 = dis[j1], d2 = dis[j2], d3 = dis[j3];
        float4 r0 = H4[(size_t)j0 * 128 + t];
        float4 r1 = H4[(size_t)j1 * 128 + t];
        float4 r2 = H4[(size_t)j2 * 128 + t];
        float4 r3 = H4[(size_t)j3 * 128 + t];
        ax += d0 * r0.x + d1 * r1.x + d2 * r2.x + d3 * r3.x;
        ay += d0 * r0.y + d1 * r1.y + d2 * r2.y + d3 * r3.y;
        az += d0 * r0.z + d1 * r1.z + d2 * r2.z + d3 * r3.z;
        aw += d0 * r0.w + d1 * r1.w + d2 * r2.w + d3 * r3.w;
    }
    for (; e < e1; e++) {
        int j = csr[e];
        float d = dis[j];
        float4 r = H4[(size_t)j * 128 + t];
        ax += d * r.x;
        ay += d * r.y;
        az += d * r.z;
        aw += d * r.w;
    }
    ax *= di; ay *= di; az *= di; aw *= di;
    short h0, l0, h1, l1, h2, l2, h3, l3;
    split_bf16(ax, h0, l0);
    split_bf16(ay, h1, l1);
    split_bf16(az, h2, l2);
    split_bf16(aw, h3, l3);
    *(short4*)&Ahi[(size_t)i * HID + t * 4] = make_short4(h0, h1, h2, h3);
    *(short4*)&Alo[(size_t)i * HID + t * 4] = make_short4(l0, l1, l2, l3);
}

// -------- split-bf16 MFMA GEMM: C[M,N] = A[M,K] @ W[N,K]^T + bias --------
// A,W given as bf16 hi/lo planes. 3 products: hi*hi + hi*lo + lo*hi.
// Tile 128x128, BK=32, 256 threads (4 waves). LDS in MFMA-fragment order
// (wave-uniform base + lane*16 matches global_load_lds semantics, and
// ds_read_b128 at base+lane*16 is conflict-free).
__global__ __launch_bounds__(256) void gemm_mfma_kernel(
    const short* __restrict__ Ahi, const short* __restrict__ Alo,
    const short* __restrict__ Whi, const short* __restrict__ Wlo,
    const float* __restrict__ bias, float* __restrict__ C,
    int M, int K, int Nout) {
    // 4 planes x (8 subtiles x 64 lanes x 8 shorts) = 4 x 8KB
    __shared__ __attribute__((aligned(16))) short lds[4][4096];

    int tid = threadIdx.x;
    int w = tid >> 6, l = tid & 63;
    int m0 = blockIdx.x * 128, n0 = blockIdx.y * 128;
    int lrow = l & 15, lq = l >> 4;

    const short* gp = (w == 0) ? Ahi : (w == 1) ? Alo : (w == 2) ? Whi : Wlo;
    int base_mn = (w < 2) ? m0 : n0;

    f32x4 acc[4][4];
    #pragma unroll
    for (int i = 0; i < 4; i++)
        #pragma unroll
        for (int j = 0; j < 4; j++) acc[i][j] = (f32x4){0.f, 0.f, 0.f, 0.f};

    int wm = w >> 1, wn = w & 1;

    for (int k0 = 0; k0 < K; k0 += 32) {
        // stage: wave w stages its plane, 8 subtiles of 16 rows
        const short* gbase = gp + (size_t)(base_mn + lrow) * K + (k0 + lq * 8);
        #pragma unroll
        for (int s = 0; s < 8; s++) {
            gload_lds16(gbase + (size_t)s * 16 * K, &lds[w][s * 64 * 8]);
        }
        __syncthreads();

        bf16x8 ah[4], al[4], wh[4], wl[4];
        #pragma unroll
        for (int i = 0; i < 4; i++) {
            int sA = wm * 4 + i;
            ah[i] = *(const bf16x8*)&lds[0][(sA * 64 + l) * 8];
            al[i] = *(const bf16x8*)&lds[1][(sA * 64 + l) * 8];
            int sW = wn * 4 + i;
            wh[i] = *(const bf16x8*)&lds[2][(sW * 64 + l) * 8];
            wl[i] = *(const bf16x8*)&lds[3][(sW * 64 + l) * 8];
        }
        #pragma unroll
        for (int i = 0; i < 4; i++)
            #pragma unroll
            for (int j = 0; j < 4; j++) {
                acc[i][j] = __builtin_amdgcn_mfma_f32_16x16x32_bf16(ah[i], wh[j], acc[i][j], 0, 0, 0);
                acc[i][j] = __builtin_amdgcn_mfma_f32_16x16x32_bf16(ah[i], wl[j], acc[i][j], 0, 0, 0);
                acc[i][j] = __builtin_amdgcn_mfma_f32_16x16x32_bf16(al[i], wh[j], acc[i][j], 0, 0, 0);
            }
        __syncthreads();
    }

    // epilogue: C/D layout col=lane&15, row=(lane>>4)*4+reg
    #pragma unroll
    for (int j = 0; j < 4; j++) {
        int col = n0 + (wn * 4 + j) * 16 + lrow;
        float bv = bias[col];
        #pragma unroll
        for (int i = 0; i < 4; i++) {
            int mrow = m0 + (wm * 4 + i) * 16 + lq * 4;
            #pragma unroll
            for (int r = 0; r < 4; r++) {
                int mm = mrow + r;
                if (mm < M) C[(size_t)mm * Nout + col] = acc[i][j][r] + bv;
            }
        }
    }
}

// ---------------- pooling ----------------
__global__ void pool_kernel(const float* __restrict__ H, const int* __restrict__ starts,
                            float* __restrict__ out, int layer) {
    int g = blockIdx.x;
    int c = blockIdx.y * 256 + threadIdx.x;  // 0..511
    int s = starts[g], e = starts[g + 1];
    float mx = -INFINITY;
    int pos = 0;
    #pragma unroll 4
    for (int n = s; n < e; n++) {
        float v = H[(size_t)n * HID + c];
        mx = fmaxf(mx, v);
        pos += (v > 0.0f) ? 1 : 0;
    }
    float cntf = fmaxf((float)(e - s), 1.0f);
    out[(size_t)g * (8 * HID) + layer * HID + c] = mx;
    out[(size_t)g * (8 * HID) + 4 * HID + layer * HID + c] = (float)pos / cntf;
}

// ---------------- launcher ----------------
extern "C" void kernel_launch(void* const* d_in, const int* in_sizes, int n_in,
                              void* d_out, int out_size, void* d_ws, size_t ws_size,
                              hipStream_t stream) {
    const float* x     = (const float*)d_in[0];
    const int*   eidx  = (const int*)d_in[1];
    const int*   batch = (const int*)d_in[2];
    const float* W1 = (const float*)d_in[5];
    const float* b1 = (const float*)d_in[6];
    const float* W2 = (const float*)d_in[7];
    const float* b2 = (const float*)d_in[8];
    const float* W3 = (const float*)d_in[9];
    const float* b3 = (const float*)d_in[10];
    const float* W4 = (const float*)d_in[11];
    const float* b4 = (const float*)d_in[12];
    float* out = (float*)d_out;

    const int N = in_sizes[0] / F_IN;   // 20000
    const int E = in_sizes[1] / 2;      // 320000
    const int G = out_size / (8 * HID); // 256

    const int* src = eidx;
    const int* dst = eidx + E;

    // workspace layout (16B-aligned segments first)
    char* w = (char*)d_ws;
    short* Ahi = (short*)w; w += (size_t)N * HID * sizeof(short);   // 20.48 MB
    short* Alo = (short*)w; w += (size_t)N * HID * sizeof(short);   // 20.48 MB
    float* H   = (float*)w; w += (size_t)N * HID * sizeof(float);   // 40.96 MB
    short* Whi = (short*)w; w += (size_t)HID * HID * sizeof(short); // 0.5 MB
    short* Wlo = (short*)w; w += (size_t)HID * HID * sizeof(short); // 0.5 MB
    int* offs  = (int*)w;   w += (size_t)(N + 4) * sizeof(int);
    unsigned short* csr = (unsigned short*)w; w += (size_t)E * sizeof(unsigned short);
    int* cnt   = (int*)w;   w += (size_t)N * sizeof(int);
    float* dis = (float*)w; w += (size_t)N * sizeof(float);
    int* starts = (int*)w;  w += (size_t)(G + 1) * sizeof(int);

    const int TB = 256;
    // ---- preprocessing: CSR over dst, dis, graph boundaries ----
    zero_kernel<<<(N + TB - 1) / TB, TB, 0, stream>>>(cnt, N);
    count_in_kernel<<<(E + TB - 1) / TB, TB, 0, stream>>>(dst, cnt, E);
    scan_kernel<<<1, 1024, 0, stream>>>(cnt, offs, N);
    dis_kernel<<<(N + TB - 1) / TB, TB, 0, stream>>>(offs, dis, N);
    zero_kernel<<<(N + TB - 1) / TB, TB, 0, stream>>>(cnt, N);  // reuse as cursor
    fill_csr_kernel<<<(E + TB - 1) / TB, TB, 0, stream>>>(src, dst, offs, cnt, csr, E);
    starts_kernel<<<(N + TB - 1) / TB, TB, 0, stream>>>(batch, starts, N, G);

    dim3 gemm_grid((N + 127) / 128, HID / 128);
    dim3 pool_grid(G, HID / 256);

    // ---- layer 1: h1 = (A x) @ W1^T + b1 ----
    wconv_kernel<<<(HID * F_IN + TB - 1) / TB, TB, 0, stream>>>(W1, Whi, Wlo, HID * F_IN);
    agg_f128_kernel<<<N, 64, 0, stream>>>(x, dis, offs, csr, Ahi, Alo, N);
    gemm_mfma_kernel<<<gemm_grid, 256, 0, stream>>>(Ahi, Alo, Whi, Wlo, b1, H, N, F_IN, HID);
    pool_kernel<<<pool_grid, 256, 0, stream>>>(H, starts, out, 0);

    // ---- layers 2..4 ----
    const float* Ws_[3] = {W2, W3, W4};
    const float* bs_[3] = {b2, b3, b4};
    for (int ll = 0; ll < 3; ll++) {
        wconv_kernel<<<(HID * HID + TB - 1) / TB, TB, 0, stream>>>(Ws_[ll], Whi, Wlo, HID * HID);
        agg_f512_kernel<<<N, 128, 0, stream>>>(H, dis, offs, csr, Ahi, Alo, N);
        gemm_mfma_kernel<<<gemm_grid, 256, 0, stream>>>(Ahi, Alo, Whi, Wlo, bs_[ll], H, N, HID, HID);
        pool_kernel<<<pool_grid, 256, 0, stream>>>(H, starts, out, ll + 1);
    }
}

// Round 3
// 686.237 us; speedup vs baseline: 1.5195x; 1.0685x over previous
//
#include <hip/hip_runtime.h>
#include <cfloat>
#include <cmath>

#define F_IN 128
#define HID 512

typedef short bf16x8 __attribute__((ext_vector_type(8)));
typedef float f32x4 __attribute__((ext_vector_type(4)));

// ---- bf16 split helpers (RNE) ----
__device__ static inline void split_bf16(float v, short& hi, short& lo) {
    unsigned u = __float_as_uint(v);
    unsigned r = u + 0x7FFF + ((u >> 16) & 1);
    hi = (short)(r >> 16);
    float hf = __uint_as_float(((unsigned)(unsigned short)hi) << 16);
    float res = v - hf;
    unsigned u2 = __float_as_uint(res);
    unsigned r2 = u2 + 0x7FFF + ((u2 >> 16) & 1);
    lo = (short)(r2 >> 16);
}

__device__ static inline void gload_lds16(const void* g, void* l) {
    __builtin_amdgcn_global_load_lds(
        (const __attribute__((address_space(1))) unsigned int*)g,
        (__attribute__((address_space(3))) unsigned int*)l,
        16, 0, 0);
}

// ---------------- small utility kernels ----------------

__global__ void zero_kernel(int* __restrict__ a, int n) {
    int i = blockIdx.x * blockDim.x + threadIdx.x;
    if (i < n) a[i] = 0;
}

__global__ void count_in_kernel(const int* __restrict__ dst, int* __restrict__ cnt, int E) {
    int e = blockIdx.x * blockDim.x + threadIdx.x;
    if (e < E) atomicAdd(&cnt[dst[e]], 1);
}

// single-block scan (exclusive prefix sum); also writes offs[n] = total
__global__ void scan_kernel(const int* __restrict__ cnt, int* __restrict__ offs, int n) {
    __shared__ int buf[1024];
    __shared__ int carry_s;
    if (threadIdx.x == 0) carry_s = 0;
    __syncthreads();
    for (int base = 0; base < n; base += 1024) {
        int i = base + threadIdx.x;
        int v = (i < n) ? cnt[i] : 0;
        buf[threadIdx.x] = v;
        __syncthreads();
        for (int s = 1; s < 1024; s <<= 1) {
            int t = (threadIdx.x >= s) ? buf[threadIdx.x - s] : 0;
            __syncthreads();
            buf[threadIdx.x] += t;
            __syncthreads();
        }
        int total = buf[1023];
        if (i < n) offs[i] = carry_s + buf[threadIdx.x] - v;
        __syncthreads();
        if (threadIdx.x == 0) carry_s += total;
        __syncthreads();
    }
    if (threadIdx.x == 0) offs[n] = carry_s;
}

__global__ void dis_kernel(const int* __restrict__ offs, float* __restrict__ dis, int n) {
    int i = blockIdx.x * blockDim.x + threadIdx.x;
    if (i < n) dis[i] = rsqrtf((float)(offs[i + 1] - offs[i] + 1));  // +1 self-loop
}

// countdown-cursor fill: reuses cnt (holds deg) as cursor via atomicSub
__global__ void fill_csr_kernel(const int* __restrict__ src, const int* __restrict__ dst,
                                const int* __restrict__ offs, int* __restrict__ cnt,
                                unsigned short* __restrict__ csr, int E) {
    int e = blockIdx.x * blockDim.x + threadIdx.x;
    if (e < E) {
        int d = dst[e];
        int p = atomicSub(&cnt[d], 1);  // returns old value in [1, deg]
        csr[offs[d] + p - 1] = (unsigned short)src[e];
    }
}

__global__ void starts_kernel(const int* __restrict__ batch, int* __restrict__ starts,
                              int n, int G) {
    int i = blockIdx.x * blockDim.x + threadIdx.x;
    if (i >= n) return;
    int b = batch[i];
    if (i == 0) {
        for (int g = 0; g <= b; g++) starts[g] = 0;
    } else {
        int bp = batch[i - 1];
        for (int g = bp + 1; g <= b; g++) starts[g] = i;
    }
    if (i == n - 1) {
        for (int g = b + 1; g <= G; g++) starts[g] = n;
    }
}

// all-layer W fp32 -> bf16 hi/lo planes (single launch, concatenated)
__global__ void wconv_kernel(const float* __restrict__ W1, const float* __restrict__ W2,
                             const float* __restrict__ W3, const float* __restrict__ W4,
                             short* __restrict__ Whi, short* __restrict__ Wlo) {
    int i = blockIdx.x * blockDim.x + threadIdx.x;
    const int n1 = HID * F_IN, nk = HID * HID;
    float v;
    if (i < n1) v = W1[i];
    else if (i < n1 + nk) v = W2[i - n1];
    else if (i < n1 + 2 * nk) v = W3[i - n1 - nk];
    else if (i < n1 + 3 * nk) v = W4[i - n1 - 2 * nk];
    else return;
    short h, l;
    split_bf16(v, h, l);
    Whi[i] = h;
    Wlo[i] = l;
}

// -------- XCD-affine chunked aggregation + fused bf16-pair conversion --------
// out_i = dis_i * (dis_i*H_i + sum_j dis_j*H_j), written as bf16 hi/lo planes.
// Feature dim split into CHUNKS chunks of 64; blk = node*CHUNKS + chunk so that
// chunk == blk % CHUNKS tracks the round-robin workgroup->XCD mapping: each XCD's
// L2 only sees its own 20000 x 64 x 4B = 5.1 MB slice of H (vs 41 MB unchunked).
template <int F, int CHUNKS>
__global__ __launch_bounds__(64) void agg_chunk_kernel(
    const float* __restrict__ H, const float* __restrict__ dis,
    const int* __restrict__ offs, const unsigned short* __restrict__ csr,
    short* __restrict__ Ahi, short* __restrict__ Alo, int n) {
    int blk = blockIdx.x;
    int i = blk / CHUNKS;
    int chunk = blk % CHUNKS;
    int col = chunk * 64 + threadIdx.x;
    const float* Hc = H + col;

    float di = dis[i];
    float a = di * Hc[(size_t)i * F];
    int e = offs[i], e1 = offs[i + 1];
    // 8-way software-pipelined gather
    for (; e + 8 <= e1; e += 8) {
        int j0 = csr[e],     j1 = csr[e + 1], j2 = csr[e + 2], j3 = csr[e + 3];
        int j4 = csr[e + 4], j5 = csr[e + 5], j6 = csr[e + 6], j7 = csr[e + 7];
        float d0 = dis[j0], d1 = dis[j1], d2 = dis[j2], d3 = dis[j3];
        float d4 = dis[j4], d5 = dis[j5], d6 = dis[j6], d7 = dis[j7];
        float r0 = Hc[(size_t)j0 * F], r1 = Hc[(size_t)j1 * F];
        float r2 = Hc[(size_t)j2 * F], r3 = Hc[(size_t)j3 * F];
        float r4 = Hc[(size_t)j4 * F], r5 = Hc[(size_t)j5 * F];
        float r6 = Hc[(size_t)j6 * F], r7 = Hc[(size_t)j7 * F];
        a += d0 * r0 + d1 * r1 + d2 * r2 + d3 * r3;
        a += d4 * r4 + d5 * r5 + d6 * r6 + d7 * r7;
    }
    for (; e < e1; e++) {
        int j = csr[e];
        a += dis[j] * Hc[(size_t)j * F];
    }
    a *= di;
    short h, l;
    split_bf16(a, h, l);
    Ahi[(size_t)i * F + col] = h;
    Alo[(size_t)i * F + col] = l;
}

// -------- split-bf16 MFMA GEMM: C[M,N] = A[M,K] @ W[N,K]^T + bias --------
// A,W given as bf16 hi/lo planes. 3 products: hi*hi + hi*lo + lo*hi.
__global__ __launch_bounds__(256) void gemm_mfma_kernel(
    const short* __restrict__ Ahi, const short* __restrict__ Alo,
    const short* __restrict__ Whi, const short* __restrict__ Wlo,
    const float* __restrict__ bias, float* __restrict__ C,
    int M, int K, int Nout) {
    __shared__ __attribute__((aligned(16))) short lds[4][4096];

    int tid = threadIdx.x;
    int w = tid >> 6, l = tid & 63;
    int m0 = blockIdx.x * 128, n0 = blockIdx.y * 128;
    int lrow = l & 15, lq = l >> 4;

    const short* gp = (w == 0) ? Ahi : (w == 1) ? Alo : (w == 2) ? Whi : Wlo;
    int base_mn = (w < 2) ? m0 : n0;

    f32x4 acc[4][4];
    #pragma unroll
    for (int i = 0; i < 4; i++)
        #pragma unroll
        for (int j = 0; j < 4; j++) acc[i][j] = (f32x4){0.f, 0.f, 0.f, 0.f};

    int wm = w >> 1, wn = w & 1;

    for (int k0 = 0; k0 < K; k0 += 32) {
        const short* gbase = gp + (size_t)(base_mn + lrow) * K + (k0 + lq * 8);
        #pragma unroll
        for (int s = 0; s < 8; s++) {
            gload_lds16(gbase + (size_t)s * 16 * K, &lds[w][s * 64 * 8]);
        }
        __syncthreads();

        bf16x8 ah[4], al[4], wh[4], wl[4];
        #pragma unroll
        for (int i = 0; i < 4; i++) {
            int sA = wm * 4 + i;
            ah[i] = *(const bf16x8*)&lds[0][(sA * 64 + l) * 8];
            al[i] = *(const bf16x8*)&lds[1][(sA * 64 + l) * 8];
            int sW = wn * 4 + i;
            wh[i] = *(const bf16x8*)&lds[2][(sW * 64 + l) * 8];
            wl[i] = *(const bf16x8*)&lds[3][(sW * 64 + l) * 8];
        }
        #pragma unroll
        for (int i = 0; i < 4; i++)
            #pragma unroll
            for (int j = 0; j < 4; j++) {
                acc[i][j] = __builtin_amdgcn_mfma_f32_16x16x32_bf16(ah[i], wh[j], acc[i][j], 0, 0, 0);
                acc[i][j] = __builtin_amdgcn_mfma_f32_16x16x32_bf16(ah[i], wl[j], acc[i][j], 0, 0, 0);
                acc[i][j] = __builtin_amdgcn_mfma_f32_16x16x32_bf16(al[i], wh[j], acc[i][j], 0, 0, 0);
            }
        __syncthreads();
    }

    #pragma unroll
    for (int j = 0; j < 4; j++) {
        int col = n0 + (wn * 4 + j) * 16 + lrow;
        float bv = bias[col];
        #pragma unroll
        for (int i = 0; i < 4; i++) {
            int mrow = m0 + (wm * 4 + i) * 16 + lq * 4;
            #pragma unroll
            for (int r = 0; r < 4; r++) {
                int mm = mrow + r;
                if (mm < M) C[(size_t)mm * Nout + col] = acc[i][j][r] + bv;
            }
        }
    }
}

// ---------------- pooling ----------------
__global__ void pool_kernel(const float* __restrict__ H, const int* __restrict__ starts,
                            float* __restrict__ out, int layer) {
    int g = blockIdx.x;
    int c = blockIdx.y * 256 + threadIdx.x;  // 0..511
    int s = starts[g], e = starts[g + 1];
    float mx = -INFINITY;
    int pos = 0;
    #pragma unroll 4
    for (int n = s; n < e; n++) {
        float v = H[(size_t)n * HID + c];
        mx = fmaxf(mx, v);
        pos += (v > 0.0f) ? 1 : 0;
    }
    float cntf = fmaxf((float)(e - s), 1.0f);
    out[(size_t)g * (8 * HID) + layer * HID + c] = mx;
    out[(size_t)g * (8 * HID) + 4 * HID + layer * HID + c] = (float)pos / cntf;
}

// ---------------- launcher ----------------
extern "C" void kernel_launch(void* const* d_in, const int* in_sizes, int n_in,
                              void* d_out, int out_size, void* d_ws, size_t ws_size,
                              hipStream_t stream) {
    const float* x     = (const float*)d_in[0];
    const int*   eidx  = (const int*)d_in[1];
    const int*   batch = (const int*)d_in[2];
    const float* W1 = (const float*)d_in[5];
    const float* b1 = (const float*)d_in[6];
    const float* W2 = (const float*)d_in[7];
    const float* b2 = (const float*)d_in[8];
    const float* W3 = (const float*)d_in[9];
    const float* b3 = (const float*)d_in[10];
    const float* W4 = (const float*)d_in[11];
    const float* b4 = (const float*)d_in[12];
    float* out = (float*)d_out;

    const int N = in_sizes[0] / F_IN;   // 20000
    const int E = in_sizes[1] / 2;      // 320000
    const int G = out_size / (8 * HID); // 256

    const int* src = eidx;
    const int* dst = eidx + E;

    // workspace layout (16B-aligned segments first)
    const size_t nW = (size_t)HID * F_IN + 3 * (size_t)HID * HID;  // all four W's
    char* w = (char*)d_ws;
    short* Ahi = (short*)w; w += (size_t)N * HID * sizeof(short);   // 20.48 MB
    short* Alo = (short*)w; w += (size_t)N * HID * sizeof(short);   // 20.48 MB
    float* H   = (float*)w; w += (size_t)N * HID * sizeof(float);   // 40.96 MB
    short* Whi = (short*)w; w += nW * sizeof(short);                // 1.7 MB
    short* Wlo = (short*)w; w += nW * sizeof(short);                // 1.7 MB
    int* offs  = (int*)w;   w += (size_t)(N + 4) * sizeof(int);
    unsigned short* csr = (unsigned short*)w; w += (size_t)E * sizeof(unsigned short);
    int* cnt   = (int*)w;   w += (size_t)N * sizeof(int);
    float* dis = (float*)w; w += (size_t)N * sizeof(float);
    int* starts = (int*)w;  w += (size_t)(G + 1) * sizeof(int);

    // per-layer plane offsets into Whi/Wlo
    const size_t wo1 = 0;
    const size_t wo2 = (size_t)HID * F_IN;
    const size_t wo3 = wo2 + (size_t)HID * HID;
    const size_t wo4 = wo3 + (size_t)HID * HID;

    const int TB = 256;
    // ---- preprocessing: CSR over dst, dis, graph boundaries, W planes ----
    zero_kernel<<<(N + TB - 1) / TB, TB, 0, stream>>>(cnt, N);
    count_in_kernel<<<(E + TB - 1) / TB, TB, 0, stream>>>(dst, cnt, E);
    scan_kernel<<<1, 1024, 0, stream>>>(cnt, offs, N);
    dis_kernel<<<(N + TB - 1) / TB, TB, 0, stream>>>(offs, dis, N);
    fill_csr_kernel<<<(E + TB - 1) / TB, TB, 0, stream>>>(src, dst, offs, cnt, csr, E);
    starts_kernel<<<(N + TB - 1) / TB, TB, 0, stream>>>(batch, starts, N, G);
    wconv_kernel<<<((int)nW + TB - 1) / TB, TB, 0, stream>>>(W1, W2, W3, W4, Whi, Wlo);

    dim3 gemm_grid((N + 127) / 128, HID / 128);
    dim3 pool_grid(G, HID / 256);

    // ---- layer 1: h1 = (A x) @ W1^T + b1 ----
    agg_chunk_kernel<F_IN, 2><<<N * 2, 64, 0, stream>>>(x, dis, offs, csr, Ahi, Alo, N);
    gemm_mfma_kernel<<<gemm_grid, 256, 0, stream>>>(Ahi, Alo, Whi + wo1, Wlo + wo1, b1, H, N, F_IN, HID);
    pool_kernel<<<pool_grid, 256, 0, stream>>>(H, starts, out, 0);

    // ---- layers 2..4 ----
    const size_t wos[3] = {wo2, wo3, wo4};
    const float* bs_[3] = {b2, b3, b4};
    for (int ll = 0; ll < 3; ll++) {
        agg_chunk_kernel<HID, 8><<<N * 8, 64, 0, stream>>>(H, dis, offs, csr, Ahi, Alo, N);
        gemm_mfma_kernel<<<gemm_grid, 256, 0, stream>>>(Ahi, Alo, Whi + wos[ll], Wlo + wos[ll], bs_[ll], H, N, HID, HID);
        pool_kernel<<<pool_grid, 256, 0, stream>>>(H, starts, out, ll + 1);
    }
}